// Round 6
// baseline (310.385 us; speedup 1.0000x reference)
//
#include <hip/hip_runtime.h>
#include <hip/hip_bf16.h>
#include <stdint.h>

// SparseCrossAttention: B=4, C=64, N=4096 (H=W=64), SPARSE_FACTOR=4 (k=1024)
// Round 6: round-5 audited pipeline + coalesced K2 logit stores via LDS repack.
// f32 logits (exact top-k semantics), register-resident 4-pass radix select,
// split-bf16 MFMA QK^T, bf16 MFMA PV, P bf16 written in-place over logits.
#define SCALE 0.125f

typedef unsigned int u32;
typedef unsigned short u16;
using bf16x8 = __attribute__((ext_vector_type(8))) short;  // 8 bf16 (4 VGPRs)
using f32x4 = __attribute__((ext_vector_type(4))) float;   // 4 fp32

__device__ __forceinline__ float wave_red_sum(float v) {
#pragma unroll
  for (int o = 32; o > 0; o >>= 1) v += __shfl_down(v, o);
  return v;
}
__device__ __forceinline__ u16 f32_to_bf16(float f) {  // RNE
  u32 u = __float_as_uint(f);
  u = (u + 0x7fffu + ((u >> 16) & 1u)) >> 16;
  return (u16)u;
}
__device__ __forceinline__ float bf16_to_f32(u16 h) {
  return __uint_as_float(((u32)h) << 16);
}
// f32 bits -> order-preserving u32 key (larger key == larger float)
__device__ __forceinline__ u32 key_of32(u32 u) {
  return (u & 0x80000000u) ? ~u : (u | 0x80000000u);
}
__device__ __forceinline__ float val_of32(u32 k) {
  return __uint_as_float((k & 0x80000000u) ? (k & 0x7FFFFFFFu) : ~k);
}

// ---------------- K1: QKV projection ----------------
// Qhi/Qlo/Khi/Klo: [b][n][64c] bf16 (c contig). Vbf: [b][c][n] bf16 (n contig).
// LDS: 48 KB weights + 16 KB tile = exactly 64 KB (static limit).
__global__ __launch_bounds__(256) void sca_qkv(
    const float* __restrict__ x, const float* __restrict__ skip,
    const float* __restrict__ w_qkv, u32* __restrict__ Qhi, u32* __restrict__ Qlo,
    u32* __restrict__ Khi, u32* __restrict__ Klo, u16* __restrict__ Vbf) {
  __shared__ float wsh[192 * 64];   // 48 KB
  __shared__ float xs[64][64];      // 16 KB
  const int tid = threadIdx.x;
  const int b = blockIdx.x >> 6;
  const int n0 = (blockIdx.x & 63) << 6;
  for (int i = tid; i < 3072; i += 256)
    *(float4*)&wsh[i << 2] = *(const float4*)(w_qkv + (i << 2));
#pragma unroll
  for (int it = 0; it < 4; ++it) {
    int f4 = tid + (it << 8);
    int c = f4 >> 4, nl = (f4 & 15) << 2;
    *(float4*)&xs[c][nl] =
        *(const float4*)(x + ((size_t)b * 64 + c) * 4096 + n0 + nl);
  }
  __syncthreads();
  const int lane = tid & 63;
  const int o0 = (tid >> 6) << 4;  // 4 o-chunks of 16
  {
    float acc[16];
#pragma unroll
    for (int i = 0; i < 16; ++i) acc[i] = 0.f;
    for (int c = 0; c < 64; ++c) {
      float xv = xs[c][lane];
#pragma unroll
      for (int oo = 0; oo < 16; ++oo) acc[oo] += wsh[(o0 + oo) * 64 + c] * xv;
    }
    size_t rb = ((size_t)b * 4096 + n0 + lane) * 32 + (o0 >> 1);
    u32 ph[8], pl[8];
#pragma unroll
    for (int oo = 0; oo < 16; oo += 2) {
      u16 h0 = f32_to_bf16(acc[oo]), h1 = f32_to_bf16(acc[oo + 1]);
      u16 l0 = f32_to_bf16(acc[oo] - bf16_to_f32(h0));
      u16 l1 = f32_to_bf16(acc[oo + 1] - bf16_to_f32(h1));
      ph[oo >> 1] = (u32)h0 | ((u32)h1 << 16);
      pl[oo >> 1] = (u32)l0 | ((u32)l1 << 16);
    }
    *(int4*)&Qhi[rb] = make_int4((int)ph[0], (int)ph[1], (int)ph[2], (int)ph[3]);
    *(int4*)&Qhi[rb + 4] = make_int4((int)ph[4], (int)ph[5], (int)ph[6], (int)ph[7]);
    *(int4*)&Qlo[rb] = make_int4((int)pl[0], (int)pl[1], (int)pl[2], (int)pl[3]);
    *(int4*)&Qlo[rb + 4] = make_int4((int)pl[4], (int)pl[5], (int)pl[6], (int)pl[7]);
  }
  __syncthreads();
#pragma unroll
  for (int it = 0; it < 4; ++it) {
    int f4 = tid + (it << 8);
    int c = f4 >> 4, nl = (f4 & 15) << 2;
    *(float4*)&xs[c][nl] =
        *(const float4*)(skip + ((size_t)b * 64 + c) * 4096 + n0 + nl);
  }
  __syncthreads();
  {
    float ka[16], va[16];
#pragma unroll
    for (int i = 0; i < 16; ++i) { ka[i] = 0.f; va[i] = 0.f; }
    for (int c = 0; c < 64; ++c) {
      float sv = xs[c][lane];
#pragma unroll
      for (int oo = 0; oo < 16; ++oo) {
        ka[oo] += wsh[(64 + o0 + oo) * 64 + c] * sv;
        va[oo] += wsh[(128 + o0 + oo) * 64 + c] * sv;
      }
    }
    size_t rb = ((size_t)b * 4096 + n0 + lane) * 32 + (o0 >> 1);
    u32 ph[8], pl[8];
#pragma unroll
    for (int oo = 0; oo < 16; oo += 2) {
      u16 h0 = f32_to_bf16(ka[oo]), h1 = f32_to_bf16(ka[oo + 1]);
      u16 l0 = f32_to_bf16(ka[oo] - bf16_to_f32(h0));
      u16 l1 = f32_to_bf16(ka[oo + 1] - bf16_to_f32(h1));
      ph[oo >> 1] = (u32)h0 | ((u32)h1 << 16);
      pl[oo >> 1] = (u32)l0 | ((u32)l1 << 16);
    }
    *(int4*)&Khi[rb] = make_int4((int)ph[0], (int)ph[1], (int)ph[2], (int)ph[3]);
    *(int4*)&Khi[rb + 4] = make_int4((int)ph[4], (int)ph[5], (int)ph[6], (int)ph[7]);
    *(int4*)&Klo[rb] = make_int4((int)pl[0], (int)pl[1], (int)pl[2], (int)pl[3]);
    *(int4*)&Klo[rb + 4] = make_int4((int)pl[4], (int)pl[5], (int)pl[6], (int)pl[7]);
#pragma unroll
    for (int oo = 0; oo < 16; ++oo)
      Vbf[((size_t)b * 64 + o0 + oo) * 4096 + n0 + lane] = f32_to_bf16(va[oo]);
  }
}

// Swizzled LDS tile: 64 rows x 64 bf16 (128-B rows), 16-B slots, slot ^= row&7.
__device__ __forceinline__ void stage_tile64(u16* __restrict__ dst,
                                             const u16* __restrict__ src,
                                             int tid) {
#pragma unroll
  for (int it = 0; it < 2; ++it) {
    int ch = tid + (it << 8);
    int row = ch >> 3, slot = ch & 7;
    int4 v = *(const int4*)(src + (size_t)row * 64 + slot * 8);
    *(int4*)(dst + row * 64 + ((slot ^ (row & 7)) << 3)) = v;
  }
}
__device__ __forceinline__ bf16x8 frag64(const u16* __restrict__ base, int row,
                                         int slot) {
  return *(const bf16x8*)(base + row * 64 + ((slot ^ (row & 7)) << 3));
}

// ---------------- K2: logits(f32) = scale * Q K^T (split-bf16 MFMA) ---------
// 64x64 D-tile per block; 3 MFMAs per K-chunk (hh, hl, lh) recover f32 acc.
// C-frags repacked through (dead) staging LDS -> coalesced 256-B row stores.
__global__ __launch_bounds__(256) void sca_qk_mfma(
    const u16* __restrict__ Qhi, const u16* __restrict__ Qlo,
    const u16* __restrict__ Khi, const u16* __restrict__ Klo,
    char* __restrict__ Lb, int bbase) {
  __shared__ char smem[32768];  // Qh|Ql|Kh|Kl (4x8 KB); reused as f32 repack
  u16* Qh = (u16*)smem;
  u16* Ql = (u16*)(smem + 8192);
  u16* Kh = (u16*)(smem + 16384);
  u16* Kl = (u16*)(smem + 24576);
  float* rep = (float*)smem;  // [64][68] f32 = 17408 B, overlaps Qh/Ql/Kh
  const int tid = threadIdx.x;
  const int mt = blockIdx.x, nt = blockIdx.y, g = blockIdx.z;
  const int b = bbase + g;
  const size_t qbase = ((size_t)b * 4096 + nt * 64) * 64;
  const size_t kbase = ((size_t)b * 4096 + mt * 64) * 64;
  stage_tile64(Qh, Qhi + qbase, tid);
  stage_tile64(Ql, Qlo + qbase, tid);
  stage_tile64(Kh, Khi + kbase, tid);
  stage_tile64(Kl, Klo + kbase, tid);
  __syncthreads();
  const int w = tid >> 6, lane = tid & 63;
  const int kg = lane >> 4, lm = lane & 15;
  f32x4 acc[4];
#pragma unroll
  for (int i = 0; i < 4; ++i) acc[i] = (f32x4){0.f, 0.f, 0.f, 0.f};
  const int ra = w * 16 + lm;  // A row (Q n-row within tile)
#pragma unroll
  for (int s = 0; s < 2; ++s) {
    bf16x8 ah = frag64(Qh, ra, s * 4 + kg);
    bf16x8 al = frag64(Ql, ra, s * 4 + kg);
#pragma unroll
    for (int mc = 0; mc < 4; ++mc) {
      int rbr = mc * 16 + lm;  // B row (K m-row within tile)
      bf16x8 bh = frag64(Kh, rbr, s * 4 + kg);
      bf16x8 bl = frag64(Kl, rbr, s * 4 + kg);
      acc[mc] = __builtin_amdgcn_mfma_f32_16x16x32_bf16(ah, bh, acc[mc], 0, 0, 0);
      acc[mc] = __builtin_amdgcn_mfma_f32_16x16x32_bf16(ah, bl, acc[mc], 0, 0, 0);
      acc[mc] = __builtin_amdgcn_mfma_f32_16x16x32_bf16(al, bh, acc[mc], 0, 0, 0);
    }
  }
  // C/D: col(lane&15)->m-local, row((lane>>4)*4+reg)->n-local.
  __syncthreads();  // staging reads done; safe to overwrite smem
#pragma unroll
  for (int mc = 0; mc < 4; ++mc)
#pragma unroll
    for (int reg = 0; reg < 4; ++reg)
      rep[(w * 16 + kg * 4 + reg) * 68 + mc * 16 + lm] = acc[mc][reg] * SCALE;
  __syncthreads();
  char* rowbase = Lb + ((size_t)g * 4096 + nt * 64) * 16384 + mt * 256;
#pragma unroll
  for (int it = 0; it < 4; ++it) {
    int idx = tid + (it << 8);
    int n = idx >> 4, mo = (idx & 15) << 2;  // mo in floats
    float4 v = *(const float4*)&rep[n * 68 + mo];
    *(float4*)(rowbase + (size_t)n * 16384 + (size_t)mo * 4) = v;
  }
}

// ---------------- K3: exact top-1024 + masked softmax (f32 keys) ------------
// One block per row; 16 f32 keys/thread in registers; 4-pass 8-bit radix
// select on order-preserving u32 keys == exact jax.top_k threshold (ties
// kept). Dropped entries contribute exp(0)=1 in closed form. No max-sub
// (logits bounded ~|4.3| -> exp safe in f32). P bf16 overwrites slot head.
__device__ __forceinline__ void suffix_scan256(u32* hist, u32* wtotal, int tid,
                                               int lane, int w) {
  u32 v = hist[tid];
#pragma unroll
  for (int off = 1; off < 64; off <<= 1) {
    u32 o = __shfl_down(v, off);
    if (lane + off < 64) v += o;
  }
  if (lane == 0) wtotal[w] = v;
  __syncthreads();
  u32 carry = 0;
  for (int ww = w + 1; ww < 4; ++ww) carry += wtotal[ww];
  hist[tid] = v + carry;
  __syncthreads();
}

__global__ __launch_bounds__(256) void sca_select_softmax(char* __restrict__ Lb) {
  __shared__ u32 h8[2048];   // 8 sub-histograms x 256 bins (atomic spread)
  __shared__ u32 hist[256];
  __shared__ u32 wtotal[4];
  __shared__ u32 s_sel, s_nxt, s_inc;
  __shared__ float s_zred[4];
  const int tid = threadIdx.x;
  const int lane = tid & 63, w = tid >> 6, sub = tid & 7;
  char* rb = Lb + (size_t)blockIdx.x * 16384;
  u32 key[16];
#pragma unroll
  for (int c = 0; c < 4; ++c) {
    int4 v = *(const int4*)(rb + c * 4096 + tid * 16);
    key[c * 4 + 0] = key_of32((u32)v.x);
    key[c * 4 + 1] = key_of32((u32)v.y);
    key[c * 4 + 2] = key_of32((u32)v.z);
    key[c * 4 + 3] = key_of32((u32)v.w);
  }
  u32 kk = 1024, prefix = 0, beyond = 0;
  for (int pass = 0; pass < 4; ++pass) {
    const int shift = 24 - pass * 8;
    const u32 pmask = (pass == 0) ? 0u : (0xFFFFFFFFu << (shift + 8));
    for (int i = tid; i < 2048; i += 256) h8[i] = 0;
    __syncthreads();
#pragma unroll
    for (int j = 0; j < 16; ++j)
      if ((key[j] & pmask) == prefix)
        atomicAdd(&h8[(((key[j] >> shift) & 255u) << 3) + sub], 1u);
    __syncthreads();
    {
      u32 t = 0;
#pragma unroll
      for (int s = 0; s < 8; ++s) t += h8[(tid << 3) + s];
      hist[tid] = t;
    }
    __syncthreads();
    suffix_scan256(hist, wtotal, tid, lane, w);
    {
      u32 inc = hist[tid], nxt = (tid < 255) ? hist[tid + 1] : 0u;
      if (kk > nxt && kk <= inc) { s_sel = (u32)tid; s_nxt = nxt; s_inc = inc; }
    }
    __syncthreads();
    prefix |= (s_sel << shift);
    beyond += s_nxt;
    kk -= s_nxt;
    __syncthreads();
  }
  const u32 thr = prefix;                       // exact k-th largest key
  const u32 kept = beyond - s_nxt + s_inc;      // # keys >= thr (ties kept)
  float z = 0.f;
#pragma unroll
  for (int j = 0; j < 16; ++j)
    if (key[j] >= thr) z += __expf(val_of32(key[j]));
  z = wave_red_sum(z);
  if (lane == 0) s_zred[w] = z;
  __syncthreads();
  const float Z = s_zred[0] + s_zred[1] + s_zred[2] + s_zred[3] +
                  (float)(4096u - kept);
  const float rinv = 1.0f / Z;
  // overwrite slot head with P (bf16, 8 KB); all reads done (syncs above)
#pragma unroll
  for (int c = 0; c < 4; ++c) {
    u32 o0, o1;
    {
      float p0 = (key[c * 4 + 0] >= thr) ? __expf(val_of32(key[c * 4 + 0])) * rinv : rinv;
      float p1 = (key[c * 4 + 1] >= thr) ? __expf(val_of32(key[c * 4 + 1])) * rinv : rinv;
      float p2 = (key[c * 4 + 2] >= thr) ? __expf(val_of32(key[c * 4 + 2])) * rinv : rinv;
      float p3 = (key[c * 4 + 3] >= thr) ? __expf(val_of32(key[c * 4 + 3])) * rinv : rinv;
      o0 = (u32)f32_to_bf16(p0) | ((u32)f32_to_bf16(p1) << 16);
      o1 = (u32)f32_to_bf16(p2) | ((u32)f32_to_bf16(p3) << 16);
    }
    *(int2*)(rb + c * 2048 + tid * 8) = make_int2((int)o0, (int)o1);
  }
}

// ---------------- K4a: part[c][n] = sum_m P[n][m] V[c][m] (bf16 MFMA) -------
__global__ __launch_bounds__(256) void sca_pv_mfma(
    const char* __restrict__ Lb, const u16* __restrict__ Vbf,
    float* __restrict__ part, int bbase) {
  __shared__ u16 Vs[4096], Ps[4096];  // 8 KB each, swizzled 64x64 tiles
  const int tid = threadIdx.x;
  const int nt = blockIdx.x, sp = blockIdx.y, g = blockIdx.z;
  const int b = bbase + g;
  const int w = tid >> 6, lane = tid & 63;
  const int kg = lane >> 4, lm = lane & 15;
  f32x4 acc[4];
#pragma unroll
  for (int i = 0; i < 4; ++i) acc[i] = (f32x4){0.f, 0.f, 0.f, 0.f};
  for (int mt2 = 0; mt2 < 16; ++mt2) {
    const int mbase = sp * 1024 + mt2 * 64;
#pragma unroll
    for (int it = 0; it < 2; ++it) {
      int ch = tid + (it << 8);
      int row = ch >> 3, slot = ch & 7;
      int4 v = *(const int4*)(Vbf + ((size_t)b * 64 + row) * 4096 + mbase + slot * 8);
      *(int4*)(Vs + row * 64 + ((slot ^ (row & 7)) << 3)) = v;
      const u16* pr =
          (const u16*)(Lb + ((size_t)g * 4096 + nt * 64 + row) * 16384) +
          mbase + slot * 8;
      int4 p = *(const int4*)pr;
      *(int4*)(Ps + row * 64 + ((slot ^ (row & 7)) << 3)) = p;
    }
    __syncthreads();
    const int rc = w * 16 + lm;  // A row (c)
#pragma unroll
    for (int s = 0; s < 2; ++s) {
      bf16x8 av = frag64(Vs, rc, s * 4 + kg);
#pragma unroll
      for (int nc = 0; nc < 4; ++nc) {
        bf16x8 bv = frag64(Ps, nc * 16 + lm, s * 4 + kg);
        acc[nc] = __builtin_amdgcn_mfma_f32_16x16x32_bf16(av, bv, acc[nc], 0, 0, 0);
      }
    }
    __syncthreads();
  }
  // C/D: col = lane&15 (n), row = (lane>>4)*4+reg (c)
#pragma unroll
  for (int nc = 0; nc < 4; ++nc) {
    int n = nt * 64 + nc * 16 + lm;
#pragma unroll
    for (int reg = 0; reg < 4; ++reg) {
      int c = w * 16 + kg * 4 + reg;
      part[(((size_t)g * 4 + sp) * 64 + c) * 4096 + n] = acc[nc][reg];
    }
  }
}

// ---------------- K4b: combine splits + w_out + bias + gamma*out + x --------
__global__ __launch_bounds__(256) void sca_epilogue(
    const float* __restrict__ part, const float* __restrict__ w_out,
    const float* __restrict__ b_out, const float* __restrict__ gamma,
    const float* __restrict__ x, float* __restrict__ out, int bbase) {
  __shared__ float wsh[4096];
  __shared__ float pv[64][65];
  const int tid = threadIdx.x;
  const int nt = blockIdx.x, g = blockIdx.y;
  const int b = bbase + g;
  for (int i = tid; i < 1024; i += 256)
    *(float4*)&wsh[i << 2] = *(const float4*)(w_out + (i << 2));
#pragma unroll
  for (int it = 0; it < 4; ++it) {
    int f4 = tid + (it << 8);
    int c = f4 >> 4, nl = (f4 & 15) << 2;
    const float* p0 = part + ((size_t)g * 4 * 64 + c) * 4096 + nt * 64 + nl;
    float4 a = *(const float4*)(p0);
    float4 d = *(const float4*)(p0 + (size_t)64 * 4096);
    float4 e = *(const float4*)(p0 + (size_t)128 * 4096);
    float4 f = *(const float4*)(p0 + (size_t)192 * 4096);
    pv[c][nl] = a.x + d.x + e.x + f.x;
    pv[c][nl + 1] = a.y + d.y + e.y + f.y;
    pv[c][nl + 2] = a.z + d.z + e.z + f.z;
    pv[c][nl + 3] = a.w + d.w + e.w + f.w;
  }
  __syncthreads();
  const int lane = tid & 63;
  const int o0 = (tid >> 6) << 4;
  const float gm = gamma[0];
#pragma unroll
  for (int og = 0; og < 4; ++og) {
    const int o = o0 + og * 4;
    float a0 = b_out[o], a1 = b_out[o + 1], a2 = b_out[o + 2], a3 = b_out[o + 3];
    for (int c = 0; c < 64; ++c) {
      float p = pv[c][lane];
      a0 += wsh[(o + 0) * 64 + c] * p;
      a1 += wsh[(o + 1) * 64 + c] * p;
      a2 += wsh[(o + 2) * 64 + c] * p;
      a3 += wsh[(o + 3) * 64 + c] * p;
    }
    size_t base = ((size_t)b * 64 + o) * 4096 + (size_t)nt * 64 + lane;
    out[base] = gm * a0 + x[base];
    out[base + 4096] = gm * a1 + x[base + 4096];
    out[base + 2 * 4096] = gm * a2 + x[base + 2 * 4096];
    out[base + 3 * 4096] = gm * a3 + x[base + 3 * 4096];
  }
}

extern "C" void kernel_launch(void* const* d_in, const int* in_sizes, int n_in,
                              void* d_out, int out_size, void* d_ws,
                              size_t ws_size, hipStream_t stream) {
  const float* x = (const float*)d_in[0];
  const float* skip = (const float*)d_in[1];
  const float* w_qkv = (const float*)d_in[2];
  const float* w_out = (const float*)d_in[3];
  const float* b_out = (const float*)d_in[4];
  const float* gamma = (const float*)d_in[5];
  float* out = (float*)d_out;
  char* ws = (char*)d_ws;
  const size_t MB = 1024ull * 1024ull;
  u32* Qhi = (u32*)ws;              // 2 MB  [b][n][32] u32 (=64 bf16)
  u32* Qlo = (u32*)(ws + 2 * MB);   // 2 MB
  u32* Khi = (u32*)(ws + 4 * MB);   // 2 MB
  u32* Klo = (u32*)(ws + 6 * MB);   // 2 MB
  u16* Vbf = (u16*)(ws + 8 * MB);   // 2 MB  [b][c][n] bf16
  // batch-group G: ws need = 10 + G*4 (partials f32) + G*64 (row slots) MB
  int G = 1;
  if ((size_t)(10 + 4 * 68) * MB <= ws_size) G = 4;
  else if ((size_t)(10 + 2 * 68) * MB <= ws_size) G = 2;
  float* part = (float*)(ws + 10 * MB);          // [G][4][64][4096] f32
  char* Lb = ws + (10 + (size_t)G * 4) * MB;     // [G*4096] slots of 16 KB:
                                                 // f32 logits, head -> bf16 P
  sca_qkv<<<dim3(256), dim3(256), 0, stream>>>(x, skip, w_qkv, Qhi, Qlo, Khi,
                                               Klo, Vbf);
  for (int bb = 0; bb < 4; bb += G) {
    sca_qk_mfma<<<dim3(64, 64, G), dim3(256), 0, stream>>>(
        (const u16*)Qhi, (const u16*)Qlo, (const u16*)Khi, (const u16*)Klo, Lb, bb);
    sca_select_softmax<<<dim3(4096 * G), dim3(256), 0, stream>>>(Lb);
    sca_pv_mfma<<<dim3(64, 4, G), dim3(256), 0, stream>>>(Lb, Vbf, part, bb);
    sca_epilogue<<<dim3(64, G), dim3(256), 0, stream>>>(part, w_out, b_out,
                                                        gamma, x, out, bb);
  }
}